// Round 7
// baseline (194.438 us; speedup 1.0000x reference)
//
#include <hip/hip_runtime.h>
#include <math.h>

// FourierConv2D: B=16,H=W=128,C=16,F=32. FFT 256x256, half-spectrum w in [0,129).
// v7: k3 uses bf16 MFMA (complex via [Re|Im] K=32 concat, one wave per point&f-tile, no LDS);
// k4/k5 re-tiled to 32 FFT rows per block (full 128B-line global access); R/T/Fimg/OF all bf16;
// twiddle product-tree (1 sincos per FFT call).

constexpr int Bn = 16, Cc = 16, Ff = 32, Hh = 128, Ww = 128, Nn = 256, WH = 129;

#define DEVINL __device__ __forceinline__
DEVINL float2 f2(float a, float b) { return make_float2(a, b); }
DEVINL float2 cmul(float2 a, float2 b) { return f2(a.x * b.x - a.y * b.y, a.x * b.y + a.y * b.x); }

// bf16 pack/unpack (round-half-up)
DEVINL unsigned short f2bf(float f) { unsigned u = __float_as_uint(f); return (unsigned short)((u + 0x8000u) >> 16); }
DEVINL float bf2f(unsigned short h) { return __uint_as_float(((unsigned)h) << 16); }
DEVINL unsigned packbf(float a, float b) { return (unsigned)f2bf(a) | ((unsigned)f2bf(b) << 16); }

typedef __attribute__((ext_vector_type(8))) short short8;
typedef __attribute__((ext_vector_type(4))) float f32x4;

// LDS map: row r, element e in [0,256). Works for 16- or 32-row tiles.
DEVINL int IDX(int r, int e) { return r * 256 + ((e + r) & 255); }

// ---- in-register 16-point FFT ----
template<int SGN>
DEVINL void fft16r(float2 v[16]) {
  float2 t;
#define SW(a,b) { t = v[a]; v[a] = v[b]; v[b] = t; }
  SW(1, 8) SW(2, 4) SW(3, 12) SW(5, 10) SW(7, 14) SW(11, 13)
#undef SW
  const float C1 = 0.92387953251128674f, C2 = 0.70710678118654752f, C3 = 0.38268343236508977f;
  const float Ct[8] = {1.f, C1, C2, C3, 0.f, -C3, -C2, -C1};
  const float St[8] = {0.f, C3, C2, C1, 1.f, C1, C2, C3};
#pragma unroll
  for (int len = 2; len <= 16; len <<= 1) {
    const int half = len >> 1, ts = 16 / len;
#pragma unroll
    for (int i = 0; i < 16; i += len) {
#pragma unroll
      for (int j = 0; j < half; ++j) {
        const float wr = Ct[j * ts];
        const float wi = (SGN > 0) ? St[j * ts] : -St[j * ts];
        float2 b = v[i + j + half];
        float2 tt = f2(wr * b.x - wi * b.y, wr * b.y + wi * b.x);
        float2 a = v[i + j];
        v[i + j]        = f2(a.x + tt.x, a.y + tt.y);
        v[i + j + half] = f2(a.x - tt.x, a.y - tt.y);
      }
    }
  }
}

// ---- 256-pt FFT middle: entry v[n1]=x[t+16*n1]; exit v[k2]=X[t+16*k2]. Row-local LDS. ----
template<int SGN>
DEVINL void fft256_mid(float2 v[16], float2* __restrict__ lds, int r, int t) {
  fft16r<SGN>(v);
  const float unit = (SGN > 0) ? 0.024543692606170259f : -0.024543692606170259f;  // 2*pi/256
  float sb, cb;
  __sincosf(unit * (float)t, &sb, &cb);
  float2 W[16];
  W[1] = f2(cb, sb);
#pragma unroll
  for (int k = 2; k < 16; ++k) W[k] = cmul(W[k >> 1], W[k - (k >> 1)]);   // product tree, depth 4
#pragma unroll
  for (int k = 1; k < 16; ++k) v[k] = cmul(v[k], W[k]);
#pragma unroll
  for (int k = 0; k < 16; ++k) lds[IDX(r, t * 16 + ((k + t) & 15))] = v[k];
#pragma unroll
  for (int n2 = 0; n2 < 16; ++n2) v[n2] = lds[IDX(r, n2 * 16 + ((t + n2) & 15))];
  fft16r<SGN>(v);
}

// ---- K1: per (b,y): 16 row FFTs over x (zero-pad in regs), keep w in [0,129) ----
// R layout: [b][w][y][c]  (bf16 pairs)
__global__ __launch_bounds__(256) void k1_rowfft(const float* __restrict__ img, ushort2* __restrict__ R) {
  __shared__ float2 lds[16 * 256];
  const int tid = threadIdx.x, r = tid >> 4, t = tid & 15;
  const int y = blockIdx.x, b = blockIdx.y;
  const float* ip = img + ((size_t)(b * Hh + y) * Ww) * Cc;
  for (int i = tid; i < Ww * Cc; i += 256) { int x = i >> 4, c = i & 15; lds[IDX(c, x)] = f2(ip[i], 0.f); }
  __syncthreads();
  float2 v[16];
#pragma unroll
  for (int j = 0; j < 8; ++j) v[j] = lds[IDX(r, t + 16 * j)];
#pragma unroll
  for (int j = 8; j < 16; ++j) v[j] = f2(0.f, 0.f);
  fft256_mid<-1>(v, lds, r, t);
#pragma unroll
  for (int k = 0; k < 8; ++k) lds[IDX(r, t + 16 * k)] = v[k];
  if (t == 0) lds[IDX(r, 128)] = v[8];
  __syncthreads();
  ushort2* rp = R + (size_t)b * WH * Hh * Cc + (size_t)y * Cc;
  for (int i = tid; i < WH * Cc; i += 256) {
    int w = i >> 4, c = i & 15;
    float2 z = lds[IDX(c, w)];
    rp[(size_t)w * Hh * Cc + c] = make_ushort2(f2bf(z.x), f2bf(z.y));
  }
}

// ---- K2: per (b,w): 16 column FFTs over y (zero-pad in regs) ----
// Fimg layout: [h][w][b][c]  (bf16 pairs)
__global__ __launch_bounds__(256) void k2_colfft(const ushort2* __restrict__ R, ushort2* __restrict__ Fimg) {
  __shared__ float2 lds[16 * 256];
  const int tid = threadIdx.x, r = tid >> 4, t = tid & 15;
  const int w = blockIdx.x, b = blockIdx.y;
  const ushort2* rp = R + ((size_t)(b * WH + w) * Hh) * Cc;
  for (int i = tid; i < Hh * Cc; i += 256) {
    int y = i >> 4, c = i & 15;
    ushort2 u = rp[i];
    lds[IDX(c, y)] = f2(bf2f(u.x), bf2f(u.y));
  }
  __syncthreads();
  float2 v[16];
#pragma unroll
  for (int j = 0; j < 8; ++j) v[j] = lds[IDX(r, t + 16 * j)];
#pragma unroll
  for (int j = 8; j < 16; ++j) v[j] = f2(0.f, 0.f);
  fft256_mid<-1>(v, lds, r, t);
#pragma unroll
  for (int k2 = 0; k2 < 16; ++k2) lds[IDX(r, t + 16 * k2)] = v[k2];
  __syncthreads();
  ushort2* fp = Fimg + (size_t)w * 256 + b * 16;
  for (int i = tid; i < Nn * Cc; i += 256) {
    int h = i >> 4, c = i & 15;
    float2 z = lds[IDX(c, h)];
    fp[(size_t)h * WH * 256 + c] = make_ushort2(f2bf(z.x), f2bf(z.y));
  }
}

// ---- K3: per (h,w): out[b,f] = sum_c A[b,c]*(Kr[f,c]+i*Ki[f,c]) via bf16 MFMA ----
// A_cat[b][k]: k<16 -> Re A[b][k], k>=16 -> Im A[b][k-16]   (M=16, K=32)
// B_real[k][f]: k<16 -> Kr[f][k], else -Ki[f][k-16];  B_imag: Ki then +Kr.   (N=16 per tile)
// One wave per (point, f-tile); 2 MFMAs/point/wave; no LDS, no barriers.
// OF layout: [w][h][b][f]  (bf16 pairs)
constexpr int K3PTS = 8;   // points per wave; block = 4 waves = 2 points-groups x 2 tiles
__global__ __launch_bounds__(256) void k3_mul(const ushort2* __restrict__ Fimg, const float* __restrict__ Kr,
                                              const float* __restrict__ Ki, ushort2* __restrict__ OF) {
  const int tid = threadIdx.x;
  const int wv = tid >> 6, ln = tid & 63;
  const int tile = wv & 1;
  const int w = blockIdx.x, h0 = blockIdx.y * 16 + (wv >> 1) * K3PTS;
  const int q = ln >> 4, fq = ln & 15, m0 = q & 1;
  const bool hi = (q >= 2);
  const int sh = hi ? 16 : 0;
  const unsigned negmask = hi ? 0x80008000u : 0u;

  uint4 a0[2], a1[2];
  float4 kr0[2], kr1[2], ki0[2], ki1[2];

  auto load = [&](int g, int p) {
    const size_t base = (size_t)(h0 + g) * WH + w;
    const uint4* ap = (const uint4*)(Fimg + base * 256);
    a0[p] = ap[fq * 4 + 2 * m0];
    a1[p] = ap[fq * 4 + 2 * m0 + 1];
    const float* krp = Kr + base * 512 + fq * 16 + tile * 256 + 8 * m0;
    const float* kip = Ki + base * 512 + fq * 16 + tile * 256 + 8 * m0;
    kr0[p] = *(const float4*)krp;  kr1[p] = *(const float4*)(krp + 4);
    ki0[p] = *(const float4*)kip;  ki1[p] = *(const float4*)(kip + 4);
  };
  auto compute = [&](int g, int p) {
    // A fragment: select re (lo16) or im (hi16) halves, pack 2 c's per dword
    union U { unsigned u[4]; short8 s; };
    U ua;
    ua.u[0] = ((a0[p].x >> sh) & 0xffffu) | (((a0[p].y >> sh) & 0xffffu) << 16);
    ua.u[1] = ((a0[p].z >> sh) & 0xffffu) | (((a0[p].w >> sh) & 0xffffu) << 16);
    ua.u[2] = ((a1[p].x >> sh) & 0xffffu) | (((a1[p].y >> sh) & 0xffffu) << 16);
    ua.u[3] = ((a1[p].z >> sh) & 0xffffu) | (((a1[p].w >> sh) & 0xffffu) << 16);
    // K fragments: cvt f32->bf16, pack pairs
    unsigned krP[4], kiP[4];
    krP[0] = packbf(kr0[p].x, kr0[p].y);  krP[1] = packbf(kr0[p].z, kr0[p].w);
    krP[2] = packbf(kr1[p].x, kr1[p].y);  krP[3] = packbf(kr1[p].z, kr1[p].w);
    kiP[0] = packbf(ki0[p].x, ki0[p].y);  kiP[1] = packbf(ki0[p].z, ki0[p].w);
    kiP[2] = packbf(ki1[p].x, ki1[p].y);  kiP[3] = packbf(ki1[p].z, ki1[p].w);
    U ubr, ubi;
#pragma unroll
    for (int j = 0; j < 4; ++j) {
      ubr.u[j] = (hi ? kiP[j] : krP[j]) ^ negmask;   // [Kr | -Ki]
      ubi.u[j] = hi ? krP[j] : kiP[j];               // [Ki |  Kr]
    }
    f32x4 accR = {0.f, 0.f, 0.f, 0.f}, accI = {0.f, 0.f, 0.f, 0.f};
    accR = __builtin_amdgcn_mfma_f32_16x16x32_bf16(ua.s, ubr.s, accR, 0, 0, 0);
    accI = __builtin_amdgcn_mfma_f32_16x16x32_bf16(ua.s, ubi.s, accI, 0, 0, 0);
    unsigned* op = (unsigned*)(OF + ((size_t)w * 256 + (h0 + g)) * 512);
#pragma unroll
    for (int reg = 0; reg < 4; ++reg)
      op[(4 * q + reg) * 32 + fq + 16 * tile] = packbf(accR[reg], accI[reg]);
  };

  load(0, 0);
#pragma unroll
  for (int g = 0; g < K3PTS; ++g) {
    if (g + 1 < K3PTS) load(g + 1, (g + 1) & 1);
    compute(g, g & 1);
  }
}

// ---- K4: per (w,b): 32 inverse column FFTs over h (all f); store y' = h-63 in [0,128) ----
// T layout: [b][y'][w][f]  (bf16 pairs)
__global__ __launch_bounds__(256) void k4_colifft(const ushort2* __restrict__ OF, ushort2* __restrict__ T) {
  __shared__ float2 lds[32 * 256];   // 64 KB
  const int tid = threadIdx.x, g = tid >> 4, t = tid & 15;
  const int w = blockIdx.x, b = blockIdx.y;
  const ushort2* ofp = OF + (size_t)w * 256 * 512 + b * 32;
  const int flc = tid & 31;
  for (int i = tid; i < Nn * 32; i += 256) {
    int h = i >> 5;
    ushort2 u = ofp[(size_t)h * 512 + flc];
    lds[IDX(flc, h)] = f2(bf2f(u.x), bf2f(u.y));
  }
  __syncthreads();
#pragma unroll
  for (int rr = 0; rr < 2; ++rr) {
    const int r = 2 * g + rr;
    float2 v[16];
#pragma unroll
    for (int j = 0; j < 16; ++j) v[j] = lds[IDX(r, t + 16 * j)];
    fft256_mid<1>(v, lds, r, t);
#pragma unroll
    for (int k2 = 3; k2 < 12; ++k2) lds[IDX(r, t + 16 * k2)] = v[k2];  // elems 48..191 cover 63..190
  }
  __syncthreads();
  ushort2* tp = T + (size_t)b * Hh * WH * Ff + (size_t)w * Ff;
  for (int i = tid; i < Hh * 32; i += 256) {
    int yp = i >> 5;
    float2 z = lds[IDX(flc, 63 + yp)];
    tp[(size_t)yp * WH * Ff + flc] = make_ushort2(f2bf(z.x), f2bf(z.y));
  }
}

// ---- K5: per (b,y'): Hermitian-extend w-spectrum, 32 inverse FFTs, Re, scale, +bias, crop x ----
__global__ __launch_bounds__(256) void k5_rowifft(const ushort2* __restrict__ T, const float* __restrict__ bias,
                                                  float* __restrict__ out) {
  __shared__ float2 lds[32 * 256];   // 64 KB
  const int tid = threadIdx.x, g = tid >> 4, t = tid & 15;
  const int yp = blockIdx.x, b = blockIdx.y;
  const ushort2* tp = T + ((size_t)(b * Hh + yp) * WH) * Ff;
  const int flc = tid & 31;
  for (int i = tid; i < WH * 32; i += 256) {
    ushort2 u = tp[i];
    lds[IDX(i & 31, i >> 5)] = f2(bf2f(u.x), bf2f(u.y));
  }
  __syncthreads();
#pragma unroll
  for (int rr = 0; rr < 2; ++rr) {
    const int r = 2 * g + rr;
    float2 v[16];
#pragma unroll
    for (int n1 = 0; n1 < 16; ++n1) {            // Hermitian mirror folded into register load
      const int c = t + 16 * n1;
      if (c <= 128) v[n1] = lds[IDX(r, c)];
      else { float2 z = lds[IDX(r, 256 - c)]; v[n1] = f2(z.x, -z.y); }
    }
    fft256_mid<1>(v, lds, r, t);
#pragma unroll
    for (int k2 = 3; k2 < 12; ++k2) lds[IDX(r, t + 16 * k2)] = v[k2];
  }
  __syncthreads();
  const float sc = 1.f / 65536.f;
  const float bv = bias[flc];
  float* op = out + ((size_t)(b * Hh + yp) * Ww) * Ff;
  for (int i = tid; i < Ww * 32; i += 256) {
    int x = i >> 5;
    op[(size_t)x * Ff + flc] = lds[IDX(flc, 63 + x)].x * sc + bv;
  }
}

extern "C" void kernel_launch(void* const* d_in, const int* in_sizes, int n_in,
                              void* d_out, int out_size, void* d_ws, size_t ws_size,
                              hipStream_t stream) {
  const float* img  = (const float*)d_in[0];
  const float* kr   = (const float*)d_in[1];
  const float* ki   = (const float*)d_in[2];
  const float* bias = (const float*)d_in[3];
  float* out = (float*)d_out;

  char* ws = (char*)d_ws;
  // region layout (lifetime-overlapped):
  //   [0, 67.6MB):     Fimg bf16 (K2->K3, 33.8MB), later T bf16 (K4->K5, 33.8MB)
  //   [67.6MB, 135MB): OF bf16 (K3->K4, 67.6MB); R bf16 (K1->K2, 16.9MB) aliases its head
  const size_t szF = (size_t)Nn * WH * Bn * Cc * sizeof(float2);   // 67,633,152
  ushort2* Fimg = (ushort2*)ws;
  ushort2* T    = (ushort2*)ws;
  ushort2* OF   = (ushort2*)(ws + szF);
  ushort2* R    = (ushort2*)(ws + szF);

  k1_rowfft <<<dim3(Hh, Bn),  256, 0, stream>>>(img, R);
  k2_colfft <<<dim3(WH, Bn),  256, 0, stream>>>(R, Fimg);
  k3_mul    <<<dim3(WH, 16),  256, 0, stream>>>(Fimg, kr, ki, OF);
  k4_colifft<<<dim3(WH, Bn),  256, 0, stream>>>(OF, T);
  k5_rowifft<<<dim3(Hh, Bn),  256, 0, stream>>>(T, bias, out);
}